// Round 5
// baseline (2860.947 us; speedup 1.0000x reference)
//
#include <hip/hip_runtime.h>

typedef __bf16 bf16x8 __attribute__((ext_vector_type(8)));
typedef float  f32x4  __attribute__((ext_vector_type(4)));

constexpr int Bb = 8, Ss = 1024, Ee = 768, Hh = 12, Ll = 6, Ff = 3072;
constexpr int TOK  = Bb * Ss;      // 8192
constexpr int NQKV = 3 * Ee;       // 2304

static __device__ __forceinline__ f32x4 mfma16(bf16x8 a, bf16x8 b, f32x4 c) {
  return __builtin_amdgcn_mfma_f32_16x16x32_bf16(a, b, c, 0, 0, 0);
}

// async global->LDS, 16B per lane. LDS dest is wave-uniform base + lane*16.
static __device__ __forceinline__ void async16(const void* g, void* l) {
  __builtin_amdgcn_global_load_lds(
      (const __attribute__((address_space(1))) unsigned int*)g,
      (__attribute__((address_space(3))) unsigned int*)l, 16, 0, 0);
}

// ---------------- embedding + positional encoding ----------------
__global__ __launch_bounds__(256) void embed_kernel(
    const int* __restrict__ ids, const float* __restrict__ emb,
    const float* __restrict__ pe, float* __restrict__ x, __bf16* __restrict__ xb)
{
  int tok = blockIdx.x;
  int s   = tok & (Ss - 1);
  int id  = ids[tok];
  const float* er = emb + (size_t)id * Ee;
  const float* pr = pe  + (size_t)s  * Ee;
  size_t base = (size_t)tok * Ee;
#pragma unroll
  for (int i = 0; i < 3; i++) {
    int e = threadIdx.x + i * 256;
    float v = er[e] + pr[e];
    x[base + e]  = v;
    xb[base + e] = (__bf16)v;
  }
}

// ---------------- weight transpose fp32 (K x N) -> bf16 (N x K) ----------------
__global__ __launch_bounds__(256) void transpose_w_kernel(
    const float* __restrict__ src, __bf16* __restrict__ dst,
    int K, int N, size_t sls, size_t dls)
{
  __shared__ float t[32][33];
  src += (size_t)blockIdx.z * sls;
  dst += (size_t)blockIdx.z * dls;
  int n0 = blockIdx.x * 32, k0 = blockIdx.y * 32;
  int c = threadIdx.x & 31, r0 = threadIdx.x >> 5;
#pragma unroll
  for (int rr = 0; rr < 32; rr += 8)
    t[r0 + rr][c] = src[(size_t)(k0 + r0 + rr) * N + n0 + c];
  __syncthreads();
#pragma unroll
  for (int rr = 0; rr < 32; rr += 8)
    dst[(size_t)(n0 + r0 + rr) * K + k0 + c] = (__bf16)t[c][r0 + rr];
}

// ---------------- MFMA GEMM: C = A(MxK) * Bt(NxK)^T + bias ----------------
// 128x128 tile, BK=64, 4 waves 2x2. KEY CHANGE vs prior rounds:
// A-fragments load DIRECT global->register (each lane's 16B IS an MFMA
// A-frag; 16 rows x 64B contiguous per wave = coalesced), double-buffered
// across the barrier in registers. Only B is staged in LDS (ring-2, the
// R2-verified XOR-swizzle pattern). This cuts LDS traffic per block-step
// from 128KB (A+B write+read) to 48KB (B write 16K + read 32K): the m97
// structure's ~900TF ceiling IS the LDS pipe (128KB/85Bcyc = 1472cyc/step
// = measured 0.61us/step), so less LDS bytes/FLOP raises the ceiling ~2.7x.
// All sync is compiler-managed (__syncthreads drains; reg prefetch gets a
// full step of latency cover). K-loop is 2x-unrolled (nk always even here).
// Split-K support: ks splits of K, fp32 partials at Cf + sp*cstride,
// bias added by split 0 only. Grid = 64 * nbt * ks, XCD-aware mapping.
template<bool OUT_BF16, bool RELU>
__global__ __launch_bounds__(256, 3) void gemm_kernel(
    const __bf16* __restrict__ A, const __bf16* __restrict__ Bt,
    const float* __restrict__ bias0, const float* __restrict__ bias1,
    const float* __restrict__ bias2, int bseg,
    float* __restrict__ Cf, __bf16* __restrict__ Cb, int M, int N, int K,
    int nbt, int ks, size_t cstride)
{
  __shared__ __align__(16) __bf16 lB[2][128 * 64];
  const int tid  = threadIdx.x;
  const int wave = tid >> 6, lane = tid & 63;
  const int quad = lane >> 4, c16 = lane & 15;
  const int wm = wave >> 1, wn = wave & 1;

  const int bid = blockIdx.x;
  const int xcd = bid & 7;
  const int lb  = bid >> 3;
  const int mb  = xcd * 8 + (lb & 7);   // M/128 == 64 always
  const int sup = lb >> 3;              // nb + nbt*sp
  const int nb  = sup % nbt;
  const int sp  = sup / nbt;
  const size_t m0 = (size_t)mb * 128, n0 = (size_t)nb * 128;

  const int kn   = K / ks;              // K-range per split
  const int kbeg = sp * kn;
  const int nk   = kn >> 6;             // BK=64 steps; always EVEN here

  f32x4 acc[4][4] = {};

  // ---- B stager (R2-verified): thread (r=tid>>3, c=tid&7) -> slot r*8+c,
  // content chunk c^(r&7) of row r; j in 0..3 adds 32 rows / 256 slots.
  const int srow = tid >> 3;
  const int gcol = ((tid & 7) ^ (srow & 7)) * 8;
  const __bf16* Bg = Bt + (n0 + srow) * K + kbeg + gcol;
  // B reader: row base%16==0 + c16; stored chunk quad^(row&7); kseg1 = ^32
  const int x0 = (quad ^ (c16 & 7)) * 8;
  const int x1 = x0 ^ 32;

  // ---- A direct-to-reg: lane (c16,quad) of wave wm reads
  // A[m0 + wm*64 + mi*16 + c16][kbeg + t*64 + s*32 + quad*8 .. +7]
  const __bf16* Aw = A + (m0 + wm * 64 + c16) * (size_t)K + kbeg + quad * 8;
  const size_t arow = (size_t)16 * K;

  bf16x8 afP[4], afQ[4], af1[4], bfr[4];

  // prologue: stage B(0) into buf0, preload A kseg0 of t=0
#pragma unroll
  for (int j = 0; j < 4; j++)
    async16(Bg + (size_t)(j * 32) * K, &lB[0][((size_t)tid + j * 256) * 8]);
#pragma unroll
  for (int mi = 0; mi < 4; mi++)
    afP[mi] = *(const bf16x8*)(Aw + mi * arow);
  __syncthreads();

  for (int t = 0; t < nk; t += 2) {
    // ---------- half-step 1: compute tile t (buf0), stage t+1 (buf1)
#pragma unroll
    for (int j = 0; j < 4; j++)
      async16(Bg + (size_t)(j * 32) * K + (t + 1) * 64,
              &lB[1][((size_t)tid + j * 256) * 8]);
#pragma unroll
    for (int mi = 0; mi < 4; mi++)
      afQ[mi] = *(const bf16x8*)(Aw + mi * arow + (t + 1) * 64);   // t+1 kseg0
#pragma unroll
    for (int mi = 0; mi < 4; mi++)
      af1[mi] = *(const bf16x8*)(Aw + mi * arow + t * 64 + 32);    // t kseg1
    {
      const __bf16* lb0 = &lB[0][0];
#pragma unroll
      for (int ni = 0; ni < 4; ni++)
        bfr[ni] = *(const bf16x8*)(lb0 + (wn * 64 + ni * 16 + c16) * 64 + x0);
      __builtin_amdgcn_s_setprio(1);
#pragma unroll
      for (int mi = 0; mi < 4; mi++)
#pragma unroll
        for (int ni = 0; ni < 4; ni++)
          acc[mi][ni] = mfma16(afP[mi], bfr[ni], acc[mi][ni]);
      __builtin_amdgcn_s_setprio(0);
#pragma unroll
      for (int ni = 0; ni < 4; ni++)
        bfr[ni] = *(const bf16x8*)(lb0 + (wn * 64 + ni * 16 + c16) * 64 + x1);
      __builtin_amdgcn_s_setprio(1);
#pragma unroll
      for (int mi = 0; mi < 4; mi++)
#pragma unroll
        for (int ni = 0; ni < 4; ni++)
          acc[mi][ni] = mfma16(af1[mi], bfr[ni], acc[mi][ni]);
      __builtin_amdgcn_s_setprio(0);
    }
    __syncthreads();

    // ---------- half-step 2: compute tile t+1 (buf1), stage t+2 (buf0)
    if (t + 2 < nk) {
#pragma unroll
      for (int j = 0; j < 4; j++)
        async16(Bg + (size_t)(j * 32) * K + (t + 2) * 64,
                &lB[0][((size_t)tid + j * 256) * 8]);
#pragma unroll
      for (int mi = 0; mi < 4; mi++)
        afP[mi] = *(const bf16x8*)(Aw + mi * arow + (t + 2) * 64); // t+2 kseg0
    }
#pragma unroll
    for (int mi = 0; mi < 4; mi++)
      af1[mi] = *(const bf16x8*)(Aw + mi * arow + (t + 1) * 64 + 32); // t+1 ks1
    {
      const __bf16* lb1 = &lB[1][0];
#pragma unroll
      for (int ni = 0; ni < 4; ni++)
        bfr[ni] = *(const bf16x8*)(lb1 + (wn * 64 + ni * 16 + c16) * 64 + x0);
      __builtin_amdgcn_s_setprio(1);
#pragma unroll
      for (int mi = 0; mi < 4; mi++)
#pragma unroll
        for (int ni = 0; ni < 4; ni++)
          acc[mi][ni] = mfma16(afQ[mi], bfr[ni], acc[mi][ni]);
      __builtin_amdgcn_s_setprio(0);
#pragma unroll
      for (int ni = 0; ni < 4; ni++)
        bfr[ni] = *(const bf16x8*)(lb1 + (wn * 64 + ni * 16 + c16) * 64 + x1);
      __builtin_amdgcn_s_setprio(1);
#pragma unroll
      for (int mi = 0; mi < 4; mi++)
#pragma unroll
        for (int ni = 0; ni < 4; ni++)
          acc[mi][ni] = mfma16(af1[mi], bfr[ni], acc[mi][ni]);
      __builtin_amdgcn_s_setprio(0);
    }
    __syncthreads();
  }

  float* Cfs = Cf + (size_t)sp * cstride;
  const bool addb = (sp == 0);
#pragma unroll
  for (int ni = 0; ni < 4; ni++) {
    int col = (int)n0 + wn * 64 + ni * 16 + c16;
    const float* bp = bias0;
    int cc = col;
    if (cc >= bseg) { bp = bias1; cc -= bseg; }
    if (cc >= bseg) { bp = bias2; cc -= bseg; }
    float bv = addb ? bp[cc] : 0.f;
#pragma unroll
    for (int mi = 0; mi < 4; mi++) {
#pragma unroll
      for (int rr = 0; rr < 4; rr++) {
        size_t row = m0 + wm * 64 + mi * 16 + quad * 4 + rr;
        float v = acc[mi][ni][rr] + bv;
        if (RELU) v = fmaxf(v, 0.f);
        if (OUT_BF16) Cb[row * N + col] = (__bf16)v;
        else          Cfs[row * N + col] = v;
      }
    }
  }
}

// ---------------- V transpose: qkv v-section -> vt[b][h][d][s] ----------------
__global__ __launch_bounds__(256) void vtrans_kernel(
    const __bf16* __restrict__ qkv, __bf16* __restrict__ vt)
{
  int tid  = blockIdx.x * 256 + threadIdx.x;
  int d    = tid & 63;
  int rest = tid >> 6;
  int sc   = rest & 127;
  int bh   = rest >> 7;          // b*12+h
  int b = bh / Hh, h = bh % Hh;
  const __bf16* src = qkv + (size_t)(b * Ss + sc * 8) * NQKV + 2 * Ee + h * 64 + d;
  bf16x8 v;
#pragma unroll
  for (int i = 0; i < 8; i++) v[i] = src[(size_t)i * NQKV];
  *(bf16x8*)(vt + ((size_t)bh * 64 + d) * Ss + sc * 8) = v;
}

// ---------------- flash attention, no-max streaming softmax ----------------
// 8 waves / 512 threads per block, 128 q-rows per block (wave -> 16 rows).
__global__ __launch_bounds__(512, 6) void attn_kernel(
    const __bf16* __restrict__ qkv, const __bf16* __restrict__ vt,
    const int* __restrict__ amask, __bf16* __restrict__ out)
{
  __shared__ __align__(16) __bf16 kbuf[2][64 * 64];
  __shared__ __align__(16) __bf16 vbuf[2][64 * 64];
  __shared__ __align__(16) __bf16 plds[8][16 * 68];
  const int idx = blockIdx.x;
  const int bh = idx % 96, qi = idx / 96;     // qi in 0..7
  const int b = bh / Hh, h = bh % Hh;
  const int lane = threadIdx.x & 63, wave = threadIdx.x >> 6;
  const int quad = lane >> 4, c16 = lane & 15;
  const int q0 = qi * 128 + wave * 16;

  const __bf16* qbase = qkv + (size_t)(b * Ss + q0 + c16) * NQKV + h * 64 + quad * 8;
  bf16x8 qf0 = *(const bf16x8*)(qbase);
  bf16x8 qf1 = *(const bf16x8*)(qbase + 32);

  const int srow = threadIdx.x >> 3;          // 0..63
  const int scol = ((threadIdx.x & 7) ^ (srow & 7)) * 8;
  const __bf16* kg = qkv + (size_t)(b * Ss + srow) * NQKV + Ee + h * 64 + scol;
  const __bf16* vg = vt + ((size_t)bh * 64 + srow) * Ss + scol;

  const int sa8 = c16 & 7;
  const int rc0 = (quad ^ sa8) * 8;
  const int rc1 = ((quad + 4) ^ sa8) * 8;

  f32x4 o[4] = {};
  float lrow[4] = {0.f, 0.f, 0.f, 0.f};
  const int* mp = amask + b * Ss;
  __bf16* pw = &plds[wave][0];

  // prefetch tile 0
  async16(kg, &kbuf[0][(size_t)threadIdx.x * 8]);
  async16(vg, &vbuf[0][(size_t)threadIdx.x * 8]);

  for (int t = 0; t < 16; t++) {
    const int tb = t * 64;
    __syncthreads();
    if (t < 15) {
      const int nb = (t + 1) & 1, ntb = tb + 64;
      async16(kg + (size_t)ntb * NQKV, &kbuf[nb][(size_t)threadIdx.x * 8]);
      async16(vg + ntb,                &vbuf[nb][(size_t)threadIdx.x * 8]);
    }
    const __bf16* kb = &kbuf[t & 1][0];
    const __bf16* vb = &vbuf[t & 1][0];

    f32x4 s[4];
#pragma unroll
    for (int n = 0; n < 4; n++) {
      bf16x8 kf0 = *(const bf16x8*)(kb + (n * 16 + c16) * 64 + rc0);
      bf16x8 kf1 = *(const bf16x8*)(kb + (n * 16 + c16) * 64 + rc1);
      f32x4 z = {};
      z = mfma16(qf0, kf0, z);
      s[n] = mfma16(qf1, kf1, z);
    }
    float mk[4];
#pragma unroll
    for (int n = 0; n < 4; n++) mk[n] = mp[tb + n * 16 + c16] ? 0.f : -1e30f;

#pragma unroll
    for (int rr = 0; rr < 4; rr++) {
      float p0 = __expf(s[0][rr] * 0.125f + mk[0]);   // 1/sqrt(64)
      float p1 = __expf(s[1][rr] * 0.125f + mk[1]);
      float p2 = __expf(s[2][rr] * 0.125f + mk[2]);
      float p3 = __expf(s[3][rr] * 0.125f + mk[3]);
      lrow[rr] += (p0 + p1) + (p2 + p3);
      int prow = (quad * 4 + rr) * 68;
      pw[prow + 0  + c16] = (__bf16)p0;
      pw[prow + 16 + c16] = (__bf16)p1;
      pw[prow + 32 + c16] = (__bf16)p2;
      pw[prow + 48 + c16] = (__bf16)p3;
    }

    // P: C-layout -> A-layout via per-wave LDS roundtrip (same-wave, no barrier)
    bf16x8 pf0 = *(const bf16x8*)(pw + c16 * 68 + quad * 8);
    bf16x8 pf1 = *(const bf16x8*)(pw + c16 * 68 + 32 + quad * 8);
#pragma unroll
    for (int ni = 0; ni < 4; ni++) {
      bf16x8 vf0 = *(const bf16x8*)(vb + (ni * 16 + c16) * 64 + rc0);
      bf16x8 vf1 = *(const bf16x8*)(vb + (ni * 16 + c16) * 64 + rc1);
      o[ni] = mfma16(pf0, vf0, o[ni]);
      o[ni] = mfma16(pf1, vf1, o[ni]);
    }
  }

  // row-sum reduction across the 16 lanes holding this row's columns
#pragma unroll
  for (int rr = 0; rr < 4; rr++) {
    float sr = lrow[rr];
    sr += __shfl_xor(sr, 1);
    sr += __shfl_xor(sr, 2);
    sr += __shfl_xor(sr, 4);
    sr += __shfl_xor(sr, 8);
    float inv = 1.f / sr;
    size_t row = (size_t)(b * Ss + q0 + quad * 4 + rr) * Ee + h * 64;
    out[row + 0  + c16] = (__bf16)(o[0][rr] * inv);
    out[row + 16 + c16] = (__bf16)(o[1][rr] * inv);
    out[row + 32 + c16] = (__bf16)(o[2][rr] * inv);
    out[row + 48 + c16] = (__bf16)(o[3][rr] * inv);
  }
}

// ---------------- residual add (x + two GEMM partials) + layernorm ----------
__global__ __launch_bounds__(256) void add_ln_kernel(
    const float* __restrict__ xin, const float* __restrict__ t0,
    const float* __restrict__ t1,
    const float* __restrict__ g, const float* __restrict__ beta,
    float* __restrict__ xout, __bf16* __restrict__ xbout)
{
  __shared__ float red[8];
  size_t base = (size_t)blockIdx.x * Ee;
  float hv[3], s = 0.f, sq = 0.f;
#pragma unroll
  for (int i = 0; i < 3; i++) {
    int e = threadIdx.x + i * 256;
    hv[i] = xin[base + e] + t0[base + e] + t1[base + e];
    s += hv[i]; sq += hv[i] * hv[i];
  }
#pragma unroll
  for (int m = 1; m < 64; m <<= 1) { s += __shfl_xor(s, m); sq += __shfl_xor(sq, m); }
  int wave = threadIdx.x >> 6;
  if ((threadIdx.x & 63) == 0) { red[wave] = s; red[4 + wave] = sq; }
  __syncthreads();
  s  = red[0] + red[1] + red[2] + red[3];
  sq = red[4] + red[5] + red[6] + red[7];
  float mean = s * (1.f / Ee);
  float var  = sq * (1.f / Ee) - mean * mean;
  float rstd = rsqrtf(var + 1e-5f);
#pragma unroll
  for (int i = 0; i < 3; i++) {
    int e = threadIdx.x + i * 256;
    float v = (hv[i] - mean) * rstd * g[e] + beta[e];
    xout[base + e]  = v;
    xbout[base + e] = (__bf16)v;
  }
}

// ---------------- mean pool (stage 1) ----------------
__global__ __launch_bounds__(256) void pool1_kernel(
    const float* __restrict__ x, float* __restrict__ partial)
{
  int b = blockIdx.x, chunk = blockIdx.y;
  float acc[3] = {0.f, 0.f, 0.f};
  for (int s = chunk * 64; s < chunk * 64 + 64; s++) {
#pragma unroll
    for (int i = 0; i < 3; i++) {
      int e = threadIdx.x + i * 256;
      acc[i] += x[((size_t)b * Ss + s) * Ee + e];
    }
  }
#pragma unroll
  for (int i = 0; i < 3; i++) {
    int e = threadIdx.x + i * 256;
    partial[((size_t)b * 16 + chunk) * Ee + e] = acc[i];
  }
}

// ---------------- pool reduce + classifier ----------------
__global__ __launch_bounds__(256) void pool2_kernel(
    const float* __restrict__ partial, const float* __restrict__ Wc,
    const float* __restrict__ bc, float* __restrict__ out)
{
  __shared__ float red[8];
  int b = blockIdx.x;
  float p0 = 0.f, p1 = 0.f;
#pragma unroll
  for (int i = 0; i < 3; i++) {
    int e = threadIdx.x + i * 256;
    float pe_ = 0.f;
#pragma unroll
    for (int c = 0; c < 16; c++) pe_ += partial[((size_t)b * 16 + c) * Ee + e];
    pe_ *= (1.f / Ss);
    p0 += pe_ * Wc[e * 2 + 0];
    p1 += pe_ * Wc[e * 2 + 1];
  }
#pragma unroll
  for (int m = 1; m < 64; m <<= 1) { p0 += __shfl_xor(p0, m); p1 += __shfl_xor(p1, m); }
  int wave = threadIdx.x >> 6;
  if ((threadIdx.x & 63) == 0) { red[wave] = p0; red[4 + wave] = p1; }
  __syncthreads();
  if (threadIdx.x == 0) {
    out[b * 2 + 0] = red[0] + red[1] + red[2] + red[3] + bc[0];
    out[b * 2 + 1] = red[4] + red[5] + red[6] + red[7] + bc[1];
  }
}

extern "C" void kernel_launch(void* const* d_in, const int* in_sizes, int n_in,
                              void* d_out, int out_size, void* d_ws, size_t ws_size,
                              hipStream_t stream) {
  const int*   ids   = (const int*)  d_in[0];
  const int*   amask = (const int*)  d_in[1];
  const float* emb   = (const float*)d_in[2];
  const float* pe    = (const float*)d_in[3];
  const float* Wq    = (const float*)d_in[4];
  const float* bq    = (const float*)d_in[5];
  const float* Wk    = (const float*)d_in[6];
  const float* bk    = (const float*)d_in[7];
  const float* Wv    = (const float*)d_in[8];
  const float* bv    = (const float*)d_in[9];
  const float* Wo    = (const float*)d_in[10];
  const float* bo    = (const float*)d_in[11];
  const float* ln1g  = (const float*)d_in[12];
  const float* ln1b  = (const float*)d_in[13];
  const float* W1    = (const float*)d_in[14];
  const float* b1    = (const float*)d_in[15];
  const float* W2    = (const float*)d_in[16];
  const float* b2    = (const float*)d_in[17];
  const float* ln2g  = (const float*)d_in[18];
  const float* ln2b  = (const float*)d_in[19];
  const float* Wc    = (const float*)d_in[20];
  const float* bc    = (const float*)d_in[21];
  float* outp = (float*)d_out;

  char* p = (char*)d_ws;
  auto alloc = [&](size_t bytes) { char* r = p; p += (bytes + 255) & ~(size_t)255; return r; };
  float*  x     = (float*) alloc((size_t)TOK * Ee * 4);
  __bf16* xb    = (__bf16*)alloc((size_t)TOK * Ee * 2);
  float*  tmp   = (float*) alloc((size_t)TOK * Ee * 4);   // split partial 0
  float*  tmp2  = (float*) alloc((size_t)TOK * Ee * 4);   // split partial 1 (contig)
  __bf16* attn  = (__bf16*)alloc((size_t)TOK * Ee * 2);
  char*   r1    = alloc((size_t)TOK * Ff * 2);            // union: [qkv|vt] / h1
  __bf16* qkv   = (__bf16*)r1;
  __bf16* vt    = (__bf16*)(r1 + (size_t)TOK * NQKV * 2);
  __bf16* h1    = (__bf16*)r1;
  __bf16* wqkvt = (__bf16*)alloc((size_t)Ll * NQKV * Ee * 2);
  __bf16* wot   = (__bf16*)alloc((size_t)Ll * Ee * Ee * 2);
  __bf16* w1t   = (__bf16*)alloc((size_t)Ll * Ff * Ee * 2);
  __bf16* w2t   = (__bf16*)alloc((size_t)Ll * Ee * Ff * 2);
  float*  part  = (float*) alloc((size_t)Bb * 16 * Ee * 4);

  const size_t CSTR = (size_t)TOK * Ee;   // element stride tmp -> tmp2

  // embedding
  embed_kernel<<<TOK, 256, 0, stream>>>(ids, emb, pe, x, xb);

  // weight prep (all layers at once)
  transpose_w_kernel<<<dim3(Ee/32, Ee/32, Ll), 256, 0, stream>>>(
      Wq, wqkvt,                         Ee, Ee, (size_t)Ee*Ee, (size_t)NQKV*Ee);
  transpose_w_kernel<<<dim3(Ee/32, Ee/32, Ll), 256, 0, stream>>>(
      Wk, wqkvt + (size_t)Ee*Ee,         Ee, Ee, (size_t)Ee*Ee, (size_t)NQKV*Ee);
  transpose_w_kernel<<<dim3(Ee/32, Ee/32, Ll), 256, 0, stream>>>(
      Wv, wqkvt + (size_t)2*Ee*Ee,       Ee, Ee, (size_t)Ee*Ee, (size_t)NQKV*Ee);
  transpose_w_kernel<<<dim3(Ee/32, Ee/32, Ll), 256, 0, stream>>>(
      Wo, wot,                           Ee, Ee, (size_t)Ee*Ee, (size_t)Ee*Ee);
  transpose_w_kernel<<<dim3(Ff/32, Ee/32, Ll), 256, 0, stream>>>(
      W1, w1t,                           Ee, Ff, (size_t)Ee*Ff, (size_t)Ff*Ee);
  transpose_w_kernel<<<dim3(Ee/32, Ff/32, Ll), 256, 0, stream>>>(
      W2, w2t,                           Ff, Ee, (size_t)Ff*Ee, (size_t)Ee*Ff);

  for (int l = 0; l < Ll; l++) {
    // QKV projection (packed N=2304), bf16 out. nbt=18, ks=1.
    gemm_kernel<true, false><<<64 * (NQKV/128), 256, 0, stream>>>(
        xb, wqkvt + (size_t)l*NQKV*Ee,
        bq + l*Ee, bk + l*Ee, bv + l*Ee, Ee,
        nullptr, qkv, TOK, NQKV, Ee, NQKV/128, 1, 0);
    // V -> [b,h,d,s]
    vtrans_kernel<<<3072, 256, 0, stream>>>(qkv, vt);
    // flash attention: 8 waves/block, 128 q-rows per block
    attn_kernel<<<768, 512, 0, stream>>>(qkv, vt, amask, attn);
    // O projection, fp32 partials, split-K=2 (grid 768 -> 3 blocks/CU)
    gemm_kernel<false, false><<<64 * (Ee/128) * 2, 256, 0, stream>>>(
        attn, wot + (size_t)l*Ee*Ee,
        bo + l*Ee, bo + l*Ee, bo + l*Ee, Ee,
        tmp, nullptr, TOK, Ee, Ee, Ee/128, 2, CSTR);
    // x = LN(x + o0 + o1)
    add_ln_kernel<<<TOK, 256, 0, stream>>>(x, tmp, tmp2, ln1g + l*Ee, ln1b + l*Ee, x, xb);
    // FFN1 + relu, bf16 out. nbt=24, ks=1.
    gemm_kernel<true, true><<<64 * (Ff/128), 256, 0, stream>>>(
        xb, w1t + (size_t)l*Ff*Ee,
        b1 + l*Ff, b1 + l*Ff, b1 + l*Ff, Ff,
        nullptr, h1, TOK, Ff, Ee, Ff/128, 1, 0);
    // FFN2, fp32 partials, split-K=2 (grid 768 -> 3 blocks/CU)
    gemm_kernel<false, false><<<64 * (Ee/128) * 2, 256, 0, stream>>>(
        h1, w2t + (size_t)l*Ee*Ff,
        b2 + l*Ee, b2 + l*Ee, b2 + l*Ee, Ee,
        tmp, nullptr, TOK, Ee, Ff, Ee/128, 2, CSTR);
    // x = LN(x + f0 + f1)
    add_ln_kernel<<<TOK, 256, 0, stream>>>(x, tmp, tmp2, ln2g + l*Ee, ln2b + l*Ee, x, xb);
  }

  // mean pool + classifier
  pool1_kernel<<<dim3(Bb, 16), 256, 0, stream>>>(x, part);
  pool2_kernel<<<Bb, 256, 0, stream>>>(part, Wc, bc, outp);
}

// Round 6
// 1910.229 us; speedup vs baseline: 1.4977x; 1.4977x over previous
//
#include <hip/hip_runtime.h>

typedef __bf16 bf16x8 __attribute__((ext_vector_type(8)));
typedef float  f32x4  __attribute__((ext_vector_type(4)));

constexpr int Bb = 8, Ss = 1024, Ee = 768, Hh = 12, Ll = 6, Ff = 3072;
constexpr int TOK  = Bb * Ss;      // 8192
constexpr int NQKV = 3 * Ee;       // 2304

static __device__ __forceinline__ f32x4 mfma16(bf16x8 a, bf16x8 b, f32x4 c) {
  return __builtin_amdgcn_mfma_f32_16x16x32_bf16(a, b, c, 0, 0, 0);
}

// async global->LDS, 16B per lane. LDS dest is wave-uniform base + lane*16.
static __device__ __forceinline__ void async16(const void* g, void* l) {
  __builtin_amdgcn_global_load_lds(
      (const __attribute__((address_space(1))) unsigned int*)g,
      (__attribute__((address_space(3))) unsigned int*)l, 16, 0, 0);
}

// inline-asm ds_read_b128: invisible to the compiler's vmcnt alias tracking,
// so it cannot conservatively insert s_waitcnt vmcnt(0) before it (which
// would defeat the counted-vmcnt ring pipeline). MUST be followed by
// lgkmcnt(0) + sched_barrier(0) before any consumer (rule 18).
static __device__ __forceinline__ bf16x8 ds_read128(const __bf16* p) {
  bf16x8 r;
  unsigned a = (unsigned)(size_t)p;      // LDS pointers are 32-bit offsets
  asm volatile("ds_read_b128 %0, %1" : "=v"(r) : "v"(a));
  return r;
}

// ---------------- embedding + positional encoding ----------------
__global__ __launch_bounds__(256) void embed_kernel(
    const int* __restrict__ ids, const float* __restrict__ emb,
    const float* __restrict__ pe, float* __restrict__ x, __bf16* __restrict__ xb)
{
  int tok = blockIdx.x;
  int s   = tok & (Ss - 1);
  int id  = ids[tok];
  const float* er = emb + (size_t)id * Ee;
  const float* pr = pe  + (size_t)s  * Ee;
  size_t base = (size_t)tok * Ee;
#pragma unroll
  for (int i = 0; i < 3; i++) {
    int e = threadIdx.x + i * 256;
    float v = er[e] + pr[e];
    x[base + e]  = v;
    xb[base + e] = (__bf16)v;
  }
}

// ---------------- weight transpose fp32 (K x N) -> bf16 (N x K) ----------------
__global__ __launch_bounds__(256) void transpose_w_kernel(
    const float* __restrict__ src, __bf16* __restrict__ dst,
    int K, int N, size_t sls, size_t dls)
{
  __shared__ float t[32][33];
  src += (size_t)blockIdx.z * sls;
  dst += (size_t)blockIdx.z * dls;
  int n0 = blockIdx.x * 32, k0 = blockIdx.y * 32;
  int c = threadIdx.x & 31, r0 = threadIdx.x >> 5;
#pragma unroll
  for (int rr = 0; rr < 32; rr += 8)
    t[r0 + rr][c] = src[(size_t)(k0 + r0 + rr) * N + n0 + c];
  __syncthreads();
#pragma unroll
  for (int rr = 0; rr < 32; rr += 8)
    dst[(size_t)(n0 + r0 + rr) * K + k0 + c] = (__bf16)t[c][r0 + rr];
}

// ---------------- MFMA GEMM: C = A(MxK) * Bt(NxK)^T + bias ----------------
// 128x128 tile, BK=32, 4 waves 2x2, 4x4 MFMA per K-step.
// Ring-3 LDS pipeline with COUNTED vmcnt (T3+T4): stage tile t+2 while
// computing tile t; end-of-step waits vmcnt(4) (t+1's loads retired, t+2's
// still in flight across the raw s_barrier). 48KB LDS -> 3 blocks/CU.
// Fragment loads use INLINE-ASM ds_read_b128 so the compiler cannot insert
// its own s_waitcnt vmcnt(0) before them (it can't disambiguate ring slots
// written via global_load_lds; with compiler ds_reads that conservative
// drain silently nullified the counted wait - R4's null result).
// Rule 18: lgkmcnt(0) + sched_barrier(0) between asm ds_reads and MFMAs.
// Correctness: a slot is read one full iteration after its stage was
// issued; the previous iteration's vmcnt(4)+s_barrier guarantees all
// waves' stores to that slot retired.
// Each 128x32 tile packed as 64 LDS rows x 64 bf16 with XOR chunk swizzle
// (one lane per (row,chunk) - measured-conflict-free; numerics verified R4).
// 1D grid, XCD-aware mapping: xcd=bid&7 owns an 8-Mblock panel.
template<bool OUT_BF16, bool RELU>
__global__ __launch_bounds__(256, 3) void gemm_kernel(
    const __bf16* __restrict__ A, const __bf16* __restrict__ Bt,
    const float* __restrict__ bias0, const float* __restrict__ bias1,
    const float* __restrict__ bias2, int bseg,
    float* __restrict__ Cf, __bf16* __restrict__ Cb, int M, int N, int K)
{
  __shared__ __align__(16) __bf16 lA[3][64 * 64];
  __shared__ __align__(16) __bf16 lB[3][64 * 64];
  const int tid  = threadIdx.x;
  const int wave = tid >> 6, lane = tid & 63;
  const int quad = lane >> 4, c16 = lane & 15;
  const int wm = wave >> 1, wn = wave & 1;

  const int bid = blockIdx.x;
  const int xcd = bid & 7;
  const int lb  = bid >> 3;
  const int mb  = xcd * 8 + (lb & 7);   // M/128 == 64 always
  const int nb  = lb >> 3;
  const size_t m0 = (size_t)mb * 128, n0 = (size_t)nb * 128;

  f32x4 acc[4][4] = {};

  // stager: slots s = tid + j*256 (j=0,1); lrow=s>>3 (0..63), sch=s&7.
  // logical chunk l = sch ^ (lrow&7); tile-row tr = lrow*2 + (l>>2);
  // global col offset gq = (l&3)*8. Dest = slot*16B (linear per wave).
  const int s0l = tid >> 3;
  const int s0c = tid & 7;
  const int l0  = s0c ^ (s0l & 7);
  const int tr0 = (s0l << 1) | (l0 >> 2);
  const int gc0 = (l0 & 3) * 8;
  const int s1l = (tid + 256) >> 3;
  const int l1  = s0c ^ (s1l & 7);
  const int tr1 = (s1l << 1) | (l1 >> 2);
  const int gc1 = (l1 & 3) * 8;

  const __bf16* Ag0 = A  + (m0 + tr0) * K + gc0;
  const __bf16* Ag1 = A  + (m0 + tr1) * K + gc1;
  const __bf16* Bg0 = Bt + (n0 + tr0) * K + gc0;
  const __bf16* Bg1 = Bt + (n0 + tr1) * K + gc1;
  const int d0 = tid * 8;               // dest elems for j=0; j=1 adds 2048

  const int nk = K >> 5;

  auto stage = [&](int t, int slot) {
    const int kof = t << 5;
    async16(Ag0 + kof, &lA[slot][d0]);
    async16(Ag1 + kof, &lA[slot][d0 + 2048]);
    async16(Bg0 + kof, &lB[slot][d0]);
    async16(Bg1 + kof, &lB[slot][d0 + 2048]);
  };

  // reader offsets (elements): tile-row r = base + c16; j = r>>1;
  // chunk = ((r&1)*4 + quad) ^ (j&7); off = j*64 + chunk*8
  int aoff[4], boff[4];
#pragma unroll
  for (int f = 0; f < 4; f++) {
    int ra = wm * 64 + f * 16 + c16;
    int ja = ra >> 1;
    aoff[f] = ja * 64 + (((((ra & 1) << 2) | quad)) ^ (ja & 7)) * 8;
    int rb = wn * 64 + f * 16 + c16;
    int jb = rb >> 1;
    boff[f] = jb * 64 + (((((rb & 1) << 2) | quad)) ^ (jb & 7)) * 8;
  }

  // prologue: stage tiles 0 and 1; wait until tile 0's 4 loads retired
  stage(0, 0);
  stage(1, 1);
  asm volatile("s_waitcnt vmcnt(4)" ::: "memory");
  __builtin_amdgcn_s_barrier();
  __builtin_amdgcn_sched_barrier(0);

  int slot = 0;
  for (int t = 0; t < nk; ++t) {
    if (t + 2 < nk) {
      int ns = slot + 2; if (ns >= 3) ns -= 3;
      stage(t + 2, ns);
    }
    const __bf16* la = &lA[slot][0];
    const __bf16* lb = &lB[slot][0];
    bf16x8 af[4], bfr[4];
#pragma unroll
    for (int f = 0; f < 4; f++) af[f]  = ds_read128(la + aoff[f]);
#pragma unroll
    for (int f = 0; f < 4; f++) bfr[f] = ds_read128(lb + boff[f]);
    asm volatile("s_waitcnt lgkmcnt(0)" ::: "memory");
    __builtin_amdgcn_sched_barrier(0);
    __builtin_amdgcn_s_setprio(1);
#pragma unroll
    for (int mi = 0; mi < 4; mi++)
#pragma unroll
      for (int ni = 0; ni < 4; ni++)
        acc[mi][ni] = mfma16(af[mi], bfr[ni], acc[mi][ni]);
    __builtin_amdgcn_s_setprio(0);
    __builtin_amdgcn_sched_barrier(0);
    // counted wait: tile t+1's loads (older 4) retired; tile t+2's may fly
    if (t + 2 < nk) asm volatile("s_waitcnt vmcnt(4)" ::: "memory");
    else            asm volatile("s_waitcnt vmcnt(0)" ::: "memory");
    __builtin_amdgcn_s_barrier();
    __builtin_amdgcn_sched_barrier(0);
    slot = (slot + 1 == 3) ? 0 : slot + 1;
  }

#pragma unroll
  for (int ni = 0; ni < 4; ni++) {
    int col = (int)n0 + wn * 64 + ni * 16 + c16;
    const float* bp = bias0;
    int cc = col;
    if (cc >= bseg) { bp = bias1; cc -= bseg; }
    if (cc >= bseg) { bp = bias2; cc -= bseg; }
    float bv = bp[cc];
#pragma unroll
    for (int mi = 0; mi < 4; mi++) {
#pragma unroll
      for (int rr = 0; rr < 4; rr++) {
        size_t row = m0 + wm * 64 + mi * 16 + quad * 4 + rr;
        float v = acc[mi][ni][rr] + bv;
        if (RELU) v = fmaxf(v, 0.f);
        if (OUT_BF16) Cb[row * N + col] = (__bf16)v;
        else          Cf[row * N + col] = v;
      }
    }
  }
}

// ---------------- V transpose: qkv v-section -> vt[b][h][d][s] ----------------
__global__ __launch_bounds__(256) void vtrans_kernel(
    const __bf16* __restrict__ qkv, __bf16* __restrict__ vt)
{
  int tid  = blockIdx.x * 256 + threadIdx.x;
  int d    = tid & 63;
  int rest = tid >> 6;
  int sc   = rest & 127;
  int bh   = rest >> 7;          // b*12+h
  int b = bh / Hh, h = bh % Hh;
  const __bf16* src = qkv + (size_t)(b * Ss + sc * 8) * NQKV + 2 * Ee + h * 64 + d;
  bf16x8 v;
#pragma unroll
  for (int i = 0; i < 8; i++) v[i] = src[(size_t)i * NQKV];
  *(bf16x8*)(vt + ((size_t)bh * 64 + d) * Ss + sc * 8) = v;
}

// ---------------- flash attention, no-max streaming softmax ----------------
// 8 waves / 512 threads per block, 128 q-rows per block (wave -> 16 rows).
__global__ __launch_bounds__(512, 6) void attn_kernel(
    const __bf16* __restrict__ qkv, const __bf16* __restrict__ vt,
    const int* __restrict__ amask, __bf16* __restrict__ out)
{
  __shared__ __align__(16) __bf16 kbuf[2][64 * 64];
  __shared__ __align__(16) __bf16 vbuf[2][64 * 64];
  __shared__ __align__(16) __bf16 plds[8][16 * 68];
  const int idx = blockIdx.x;
  const int bh = idx % 96, qi = idx / 96;     // qi in 0..7
  const int b = bh / Hh, h = bh % Hh;
  const int lane = threadIdx.x & 63, wave = threadIdx.x >> 6;
  const int quad = lane >> 4, c16 = lane & 15;
  const int q0 = qi * 128 + wave * 16;

  const __bf16* qbase = qkv + (size_t)(b * Ss + q0 + c16) * NQKV + h * 64 + quad * 8;
  bf16x8 qf0 = *(const bf16x8*)(qbase);
  bf16x8 qf1 = *(const bf16x8*)(qbase + 32);

  const int srow = threadIdx.x >> 3;          // 0..63
  const int scol = ((threadIdx.x & 7) ^ (srow & 7)) * 8;
  const __bf16* kg = qkv + (size_t)(b * Ss + srow) * NQKV + Ee + h * 64 + scol;
  const __bf16* vg = vt + ((size_t)bh * 64 + srow) * Ss + scol;

  const int sa8 = c16 & 7;
  const int rc0 = (quad ^ sa8) * 8;
  const int rc1 = ((quad + 4) ^ sa8) * 8;

  f32x4 o[4] = {};
  float lrow[4] = {0.f, 0.f, 0.f, 0.f};
  const int* mp = amask + b * Ss;
  __bf16* pw = &plds[wave][0];

  // prefetch tile 0
  async16(kg, &kbuf[0][(size_t)threadIdx.x * 8]);
  async16(vg, &vbuf[0][(size_t)threadIdx.x * 8]);

  for (int t = 0; t < 16; t++) {
    const int tb = t * 64;
    __syncthreads();
    if (t < 15) {
      const int nb = (t + 1) & 1, ntb = tb + 64;
      async16(kg + (size_t)ntb * NQKV, &kbuf[nb][(size_t)threadIdx.x * 8]);
      async16(vg + ntb,                &vbuf[nb][(size_t)threadIdx.x * 8]);
    }
    const __bf16* kb = &kbuf[t & 1][0];
    const __bf16* vb = &vbuf[t & 1][0];

    f32x4 s[4];
#pragma unroll
    for (int n = 0; n < 4; n++) {
      bf16x8 kf0 = *(const bf16x8*)(kb + (n * 16 + c16) * 64 + rc0);
      bf16x8 kf1 = *(const bf16x8*)(kb + (n * 16 + c16) * 64 + rc1);
      f32x4 z = {};
      z = mfma16(qf0, kf0, z);
      s[n] = mfma16(qf1, kf1, z);
    }
    float mk[4];
#pragma unroll
    for (int n = 0; n < 4; n++) mk[n] = mp[tb + n * 16 + c16] ? 0.f : -1e30f;

#pragma unroll
    for (int rr = 0; rr < 4; rr++) {
      float p0 = __expf(s[0][rr] * 0.125f + mk[0]);   // 1/sqrt(64)
      float p1 = __expf(s[1][rr] * 0.125f + mk[1]);
      float p2 = __expf(s[2][rr] * 0.125f + mk[2]);
      float p3 = __expf(s[3][rr] * 0.125f + mk[3]);
      lrow[rr] += (p0 + p1) + (p2 + p3);
      int prow = (quad * 4 + rr) * 68;
      pw[prow + 0  + c16] = (__bf16)p0;
      pw[prow + 16 + c16] = (__bf16)p1;
      pw[prow + 32 + c16] = (__bf16)p2;
      pw[prow + 48 + c16] = (__bf16)p3;
    }

    // P: C-layout -> A-layout via per-wave LDS roundtrip (same-wave, no barrier)
    bf16x8 pf0 = *(const bf16x8*)(pw + c16 * 68 + quad * 8);
    bf16x8 pf1 = *(const bf16x8*)(pw + c16 * 68 + 32 + quad * 8);
#pragma unroll
    for (int ni = 0; ni < 4; ni++) {
      bf16x8 vf0 = *(const bf16x8*)(vb + (ni * 16 + c16) * 64 + rc0);
      bf16x8 vf1 = *(const bf16x8*)(vb + (ni * 16 + c16) * 64 + rc1);
      o[ni] = mfma16(pf0, vf0, o[ni]);
      o[ni] = mfma16(pf1, vf1, o[ni]);
    }
  }

  // row-sum reduction across the 16 lanes holding this row's columns
#pragma unroll
  for (int rr = 0; rr < 4; rr++) {
    float sr = lrow[rr];
    sr += __shfl_xor(sr, 1);
    sr += __shfl_xor(sr, 2);
    sr += __shfl_xor(sr, 4);
    sr += __shfl_xor(sr, 8);
    float inv = 1.f / sr;
    size_t row = (size_t)(b * Ss + q0 + quad * 4 + rr) * Ee + h * 64;
    out[row + 0  + c16] = (__bf16)(o[0][rr] * inv);
    out[row + 16 + c16] = (__bf16)(o[1][rr] * inv);
    out[row + 32 + c16] = (__bf16)(o[2][rr] * inv);
    out[row + 48 + c16] = (__bf16)(o[3][rr] * inv);
  }
}

// ---------------- residual add + layernorm ----------------
__global__ __launch_bounds__(256) void add_ln_kernel(
    const float* __restrict__ xin, const float* __restrict__ tmp,
    const float* __restrict__ g, const float* __restrict__ beta,
    float* __restrict__ xout, __bf16* __restrict__ xbout)
{
  __shared__ float red[8];
  size_t base = (size_t)blockIdx.x * Ee;
  float hv[3], s = 0.f, sq = 0.f;
#pragma unroll
  for (int i = 0; i < 3; i++) {
    int e = threadIdx.x + i * 256;
    hv[i] = xin[base + e] + tmp[base + e];
    s += hv[i]; sq += hv[i] * hv[i];
  }
#pragma unroll
  for (int m = 1; m < 64; m <<= 1) { s += __shfl_xor(s, m); sq += __shfl_xor(sq, m); }
  int wave = threadIdx.x >> 6;
  if ((threadIdx.x & 63) == 0) { red[wave] = s; red[4 + wave] = sq; }
  __syncthreads();
  s  = red[0] + red[1] + red[2] + red[3];
  sq = red[4] + red[5] + red[6] + red[7];
  float mean = s * (1.f / Ee);
  float var  = sq * (1.f / Ee) - mean * mean;
  float rstd = rsqrtf(var + 1e-5f);
#pragma unroll
  for (int i = 0; i < 3; i++) {
    int e = threadIdx.x + i * 256;
    float v = (hv[i] - mean) * rstd * g[e] + beta[e];
    xout[base + e]  = v;
    xbout[base + e] = (__bf16)v;
  }
}

// ---------------- mean pool (stage 1) ----------------
__global__ __launch_bounds__(256) void pool1_kernel(
    const float* __restrict__ x, float* __restrict__ partial)
{
  int b = blockIdx.x, chunk = blockIdx.y;
  float acc[3] = {0.f, 0.f, 0.f};
  for (int s = chunk * 64; s < chunk * 64 + 64; s++) {
#pragma unroll
    for (int i = 0; i < 3; i++) {
      int e = threadIdx.x + i * 256;
      acc[i] += x[((size_t)b * Ss + s) * Ee + e];
    }
  }
#pragma unroll
  for (int i = 0; i < 3; i++) {
    int e = threadIdx.x + i * 256;
    partial[((size_t)b * 16 + chunk) * Ee + e] = acc[i];
  }
}

// ---------------- pool reduce + classifier ----------------
__global__ __launch_bounds__(256) void pool2_kernel(
    const float* __restrict__ partial, const float* __restrict__ Wc,
    const float* __restrict__ bc, float* __restrict__ out)
{
  __shared__ float red[8];
  int b = blockIdx.x;
  float p0 = 0.f, p1 = 0.f;
#pragma unroll
  for (int i = 0; i < 3; i++) {
    int e = threadIdx.x + i * 256;
    float pe_ = 0.f;
#pragma unroll
    for (int c = 0; c < 16; c++) pe_ += partial[((size_t)b * 16 + c) * Ee + e];
    pe_ *= (1.f / Ss);
    p0 += pe_ * Wc[e * 2 + 0];
    p1 += pe_ * Wc[e * 2 + 1];
  }
#pragma unroll
  for (int m = 1; m < 64; m <<= 1) { p0 += __shfl_xor(p0, m); p1 += __shfl_xor(p1, m); }
  int wave = threadIdx.x >> 6;
  if ((threadIdx.x & 63) == 0) { red[wave] = p0; red[4 + wave] = p1; }
  __syncthreads();
  if (threadIdx.x == 0) {
    out[b * 2 + 0] = red[0] + red[1] + red[2] + red[3] + bc[0];
    out[b * 2 + 1] = red[4] + red[5] + red[6] + red[7] + bc[1];
  }
}

extern "C" void kernel_launch(void* const* d_in, const int* in_sizes, int n_in,
                              void* d_out, int out_size, void* d_ws, size_t ws_size,
                              hipStream_t stream) {
  const int*   ids   = (const int*)  d_in[0];
  const int*   amask = (const int*)  d_in[1];
  const float* emb   = (const float*)d_in[2];
  const float* pe    = (const float*)d_in[3];
  const float* Wq    = (const float*)d_in[4];
  const float* bq    = (const float*)d_in[5];
  const float* Wk    = (const float*)d_in[6];
  const float* bk    = (const float*)d_in[7];
  const float* Wv    = (const float*)d_in[8];
  const float* bv    = (const float*)d_in[9];
  const float* Wo    = (const float*)d_in[10];
  const float* bo    = (const float*)d_in[11];
  const float* ln1g  = (const float*)d_in[12];
  const float* ln1b  = (const float*)d_in[13];
  const float* W1    = (const float*)d_in[14];
  const float* b1    = (const float*)d_in[15];
  const float* W2    = (const float*)d_in[16];
  const float* b2    = (const float*)d_in[17];
  const float* ln2g  = (const float*)d_in[18];
  const float* ln2b  = (const float*)d_in[19];
  const float* Wc    = (const float*)d_in[20];
  const float* bc    = (const float*)d_in[21];
  float* outp = (float*)d_out;

  char* p = (char*)d_ws;
  auto alloc = [&](size_t bytes) { char* r = p; p += (bytes + 255) & ~(size_t)255; return r; };
  float*  x     = (float*) alloc((size_t)TOK * Ee * 4);
  __bf16* xb    = (__bf16*)alloc((size_t)TOK * Ee * 2);
  float*  tmp   = (float*) alloc((size_t)TOK * Ee * 4);
  __bf16* attn  = (__bf16*)alloc((size_t)TOK * Ee * 2);
  char*   r1    = alloc((size_t)TOK * Ff * 2);          // union: [qkv|vt] / h1
  __bf16* qkv   = (__bf16*)r1;
  __bf16* vt    = (__bf16*)(r1 + (size_t)TOK * NQKV * 2);
  __bf16* h1    = (__bf16*)r1;
  __bf16* wqkvt = (__bf16*)alloc((size_t)Ll * NQKV * Ee * 2);
  __bf16* wot   = (__bf16*)alloc((size_t)Ll * Ee * Ee * 2);
  __bf16* w1t   = (__bf16*)alloc((size_t)Ll * Ff * Ee * 2);
  __bf16* w2t   = (__bf16*)alloc((size_t)Ll * Ee * Ff * 2);
  float*  part  = (float*) alloc((size_t)Bb * 16 * Ee * 4);

  // embedding
  embed_kernel<<<TOK, 256, 0, stream>>>(ids, emb, pe, x, xb);

  // weight prep (all layers at once)
  transpose_w_kernel<<<dim3(Ee/32, Ee/32, Ll), 256, 0, stream>>>(
      Wq, wqkvt,                         Ee, Ee, (size_t)Ee*Ee, (size_t)NQKV*Ee);
  transpose_w_kernel<<<dim3(Ee/32, Ee/32, Ll), 256, 0, stream>>>(
      Wk, wqkvt + (size_t)Ee*Ee,         Ee, Ee, (size_t)Ee*Ee, (size_t)NQKV*Ee);
  transpose_w_kernel<<<dim3(Ee/32, Ee/32, Ll), 256, 0, stream>>>(
      Wv, wqkvt + (size_t)2*Ee*Ee,       Ee, Ee, (size_t)Ee*Ee, (size_t)NQKV*Ee);
  transpose_w_kernel<<<dim3(Ee/32, Ee/32, Ll), 256, 0, stream>>>(
      Wo, wot,                           Ee, Ee, (size_t)Ee*Ee, (size_t)Ee*Ee);
  transpose_w_kernel<<<dim3(Ff/32, Ee/32, Ll), 256, 0, stream>>>(
      W1, w1t,                           Ee, Ff, (size_t)Ee*Ff, (size_t)Ff*Ee);
  transpose_w_kernel<<<dim3(Ee/32, Ff/32, Ll), 256, 0, stream>>>(
      W2, w2t,                           Ff, Ee, (size_t)Ff*Ee, (size_t)Ee*Ff);

  for (int l = 0; l < Ll; l++) {
    // QKV projection (packed N=2304), bf16 out
    gemm_kernel<true, false><<<64 * (NQKV/128), 256, 0, stream>>>(
        xb, wqkvt + (size_t)l*NQKV*Ee,
        bq + l*Ee, bk + l*Ee, bv + l*Ee, Ee,
        nullptr, qkv, TOK, NQKV, Ee);
    // V -> [b,h,d,s]
    vtrans_kernel<<<3072, 256, 0, stream>>>(qkv, vt);
    // flash attention: 8 waves/block, 128 q-rows per block
    attn_kernel<<<768, 512, 0, stream>>>(qkv, vt, amask, attn);
    // O projection, fp32 out
    gemm_kernel<false, false><<<64 * (Ee/128), 256, 0, stream>>>(
        attn, wot + (size_t)l*Ee*Ee,
        bo + l*Ee, bo + l*Ee, bo + l*Ee, Ee,
        tmp, nullptr, TOK, Ee, Ee);
    // x = LN(x + o)
    add_ln_kernel<<<TOK, 256, 0, stream>>>(x, tmp, ln1g + l*Ee, ln1b + l*Ee, x, xb);
    // FFN1 + relu, bf16 out
    gemm_kernel<true, true><<<64 * (Ff/128), 256, 0, stream>>>(
        xb, w1t + (size_t)l*Ff*Ee,
        b1 + l*Ff, b1 + l*Ff, b1 + l*Ff, Ff,
        nullptr, h1, TOK, Ff, Ee);
    // FFN2, fp32 out
    gemm_kernel<false, false><<<64 * (Ee/128), 256, 0, stream>>>(
        h1, w2t + (size_t)l*Ee*Ff,
        b2 + l*Ee, b2 + l*Ee, b2 + l*Ee, Ee,
        tmp, nullptr, TOK, Ee, Ff);
    // x = LN(x + ffn)
    add_ln_kernel<<<TOK, 256, 0, stream>>>(x, tmp, ln2g + l*Ee, ln2b + l*Ee, x, xb);
  }

  // mean pool + classifier
  pool1_kernel<<<dim3(Bb, 16), 256, 0, stream>>>(x, part);
  pool2_kernel<<<Bb, 256, 0, stream>>>(part, Wc, bc, outp);
}